// Round 8
// baseline (193.570 us; speedup 1.0000x reference)
//
#include <hip/hip_runtime.h>

typedef float  f32x4  __attribute__((ext_vector_type(4)));
typedef __bf16 bf16x8 __attribute__((ext_vector_type(8)));
typedef unsigned short u16x4 __attribute__((ext_vector_type(4)));
typedef unsigned short u16x8 __attribute__((ext_vector_type(8)));

#define NL2E (-1.44269504088896f)   // -log2(e)
#define TL2E ( 2.88539008177793f)   // 2*log2(e)

__device__ __forceinline__ float rcpf(float x) { return __builtin_amdgcn_rcpf(x); }
__device__ __forceinline__ float ex2(float x)  { return __builtin_amdgcn_exp2f(x); }

// LSTM cell, pre-scaled gate args (zi,zf,zo = -log2e*pre, zg = 2log2e*pre)
__device__ __forceinline__ float cell_update(float zi, float zf, float zg, float zo, float& c) {
    const float Ei = ex2(zi), Ef = ex2(zf), Eg = ex2(zg), Eo = ex2(zo);
    const float ig = (Eg - 1.0f) * rcpf((1.0f + Ei) * (1.0f + Eg));
    const float fv = rcpf(1.0f + Ef);
    c = __builtin_fmaf(fv, c, ig);
    const float zc = fminf(fmaxf(TL2E * c, -60.0f), 60.0f);
    const float Ec = ex2(zc);
    return (Ec - 1.0f) * rcpf((1.0f + Eo) * (1.0f + Ec));   // o*tanh(c)
}

// 16 batches/WG, 1024 threads = 16 waves, grid 256 (4 waves/SIMD).
// B-columns PERMUTED so tile w = {(gate g, hidden 4w+(c&3)) : col c, g=c>>2}:
// each wave owns all 4 gates of 4 hiddens -> 3 MFMA/wave/step, and the 4
// gates of a cell sit on lanes q^4/q^8 -> fixed by in-wave 4x4 shfl transpose.
// Same per-SIMD work as the 4-wave kernel, but 4x the waves to overlap stalls.
__global__ __launch_bounds__(1024, 1) void lstm_fused(
    const float* __restrict__ x,      // [4096][256][16]
    const float* __restrict__ w_ih1,  // [256][16]
    const float* __restrict__ w_hh1,  // [256][64]
    const float* __restrict__ b_ih1, const float* __restrict__ b_hh1,
    const float* __restrict__ w_ih2,  // [4][64]
    const float* __restrict__ w_hh2,  // [4]
    const float* __restrict__ b_ih2, const float* __restrict__ b_hh2,
    const float* __restrict__ fc_w, const float* __restrict__ fc_b,
    float* __restrict__ out)          // [4096][256]
{
    __shared__ unsigned short A_h[2 * 16 * 64];        // 4KB dbuf h1 bf16 [buf][b][he], ^((b&7)<<4)
    __shared__ unsigned short Xc[2 * 16 * 16 * 32];    // 32KB dbuf x bf16 [buf][b][tt][k]
    __shared__ float Pre2[2][64];                      // dbuf layer-2 preacts [buf][b*4+g]
    __shared__ float Ybuf[16][16];                     // [b][tt] (wave-14 private)

    const int tid = threadIdx.x;
    const int w   = tid >> 6;        // wave 0..15
    const int l   = tid & 63;
    const int q   = l & 15;
    const int hi  = l >> 4;
    const int b0  = blockIdx.x << 4;
    const int sw  = (q & 7) << 4;
    const u16x8 z8 = {0,0,0,0,0,0,0,0};

    if (tid < 256) ((u16x8*)A_h)[tid] = z8;            // zero both A_h bufs
    {   // zero Xc pad halves (k=16..31), both bufs, once
        const int buf = tid >> 9, zb = (tid >> 5) & 15, ztt = (tid >> 1) & 15, zh = tid & 1;
        *(u16x8*)((char*)Xc + buf * 16384 + zb * 1024
                  + ((ztt * 64 + 32 + zh * 16) ^ ((zb & 7) << 4))) = z8;
    }

    // ---- permuted-column B fragment (1 tile/wave), pre-scaled ----
    const int gq = q >> 2;                             // gate of this lane's column
    const int gate_col = (gq << 6) + (w << 2) + (q & 3);
    const float sc = (gq == 2) ? TL2E : NL2E;
    bf16x8 Bf[3];
    #pragma unroll
    for (int ks = 0; ks < 3; ++ks) {
        bf16x8 tmp;
        #pragma unroll
        for (int j = 0; j < 8; ++j) {
            const int k = ks * 32 + hi * 8 + j;
            float v = 0.f;
            if (k < 64)      v = w_hh1[gate_col * 64 + k];
            else if (k < 80) v = w_ih1[gate_col * 16 + (k - 64)];
            tmp[j] = (__bf16)(sc * v);
        }
        Bf[ks] = tmp;
    }
    bf16x8 B2[2];                                      // layer-2 proj (used by wave 15)
    {
        const float sc2 = (q == 2) ? TL2E : NL2E;
        #pragma unroll
        for (int ks = 0; ks < 2; ++ks) {
            bf16x8 tmp;
            #pragma unroll
            for (int j = 0; j < 8; ++j) {
                const int k = ks * 32 + hi * 8 + j;
                const float v = (q < 4) ? w_ih2[q * 64 + k] : 0.f;
                tmp[j] = (__bf16)(sc2 * v);
            }
            B2[ks] = tmp;
        }
    }
    const float accb = sc * (b_ih1[gate_col] + b_hh1[gate_col]);   // scalar (1 col/lane)

    // layer-2 constants (scaled)
    const float w2si = NL2E * w_hh2[0], w2sf = NL2E * w_hh2[1];
    const float w2sg = TL2E * w_hh2[2], w2so = NL2E * w_hh2[3];
    const float nb2i = NL2E * (b_ih2[0] + b_hh2[0]);
    const float nb2f = NL2E * (b_ih2[1] + b_hh2[1]);
    const float tb2g = TL2E * (b_ih2[2] + b_hh2[2]);
    const float nb2o = NL2E * (b_ih2[3] + b_hh2[3]);
    const float fcw = fc_w[0], fcb = fc_b[0];

    // ---- x staging: thread (bx,part,qu) owns x[b0+bx][t0+part][qu*4..+3] ----
    const int bx = tid >> 6, part = (tid >> 2) & 15, qu = tid & 3;
    const unsigned xoff = (unsigned)(bx * 1024 + ((part * 64 + qu * 8) ^ ((bx & 7) << 4)));
    const float* xrow = x + (size_t)(b0 + bx) * 4096 + part * 16 + qu * 4;
    f32x4 xq;
    auto stage_x = [&](int bufoff) {
        u16x4 v;
        #pragma unroll
        for (int j = 0; j < 4; ++j) v[j] = __builtin_bit_cast(unsigned short, (__bf16)xq[j]);
        *(u16x4*)((char*)Xc + bufoff + xoff) = v;
    };
    xq = *(const f32x4*)xrow;
    stage_x(0);
    xq = *(const f32x4*)(xrow + 256);                  // prefetch chunk 1

    // invariant addresses
    const unsigned ar0 = (unsigned)((q * 128 +      hi * 16) ^ sw);
    const unsigned ar1 = (unsigned)((q * 128 + 64 + hi * 16) ^ sw);
    const int bb = (hi << 2) + gq;                     // batch this lane owns post-transpose
    const int he = (w << 2) + (q & 3);                 // hidden this lane owns
    const unsigned awh = (unsigned)(bb * 128 + ((he * 2) ^ ((bb & 7) << 4)));

    float cc = 0.f, h2 = 0.f, c2 = 0.f;
    __syncthreads();

    #pragma unroll 2
    for (int t = 0; t < 256; ++t) {
        const int tt = t & 15;
        if (tt == 0 && t + 16 < 256) {
            stage_x(((((t >> 4) + 1) & 1)) << 14);
            if (t + 32 < 256) xq = *(const f32x4*)(xrow + (t + 32) * 16);
        }

        const int rb = ((t + 1) & 1) << 11;
        const u16x8 ra0 = *(const u16x8*)((const char*)A_h + rb + ar0);
        const u16x8 ra1 = *(const u16x8*)((const char*)A_h + rb + ar1);
        const u16x8 ra2 = *(const u16x8*)((const char*)Xc + (((t >> 4) & 1) << 14)
                                          + ((q * 1024 + (tt << 6) + (hi << 4)) ^ sw));
        f32x4 p2;
        if (w == 14 && l < 16) p2 = *(const f32x4*)&Pre2[(t + 1) & 1][l << 2];

        const bf16x8 a0 = __builtin_bit_cast(bf16x8, ra0);
        const bf16x8 a1 = __builtin_bit_cast(bf16x8, ra1);
        const bf16x8 a2 = __builtin_bit_cast(bf16x8, ra2);

        f32x4 g = {accb, accb, accb, accb};
        g = __builtin_amdgcn_mfma_f32_16x16x32_bf16(a2, Bf[2], g, 0, 0, 0);
        g = __builtin_amdgcn_mfma_f32_16x16x32_bf16(a0, Bf[0], g, 0, 0, 0);
        g = __builtin_amdgcn_mfma_f32_16x16x32_bf16(a1, Bf[1], g, 0, 0, 0);

        if (w == 15) {   // layer-2 input projection of h_{t-1} -> Pre2[t&1]
            f32x4 p4 = {0.f, 0.f, 0.f, 0.f};
            p4 = __builtin_amdgcn_mfma_f32_16x16x32_bf16(a0, B2[0], p4, 0, 0, 0);
            p4 = __builtin_amdgcn_mfma_f32_16x16x32_bf16(a1, B2[1], p4, 0, 0, 0);
            if (q < 4) {
                #pragma unroll
                for (int r = 0; r < 4; ++r) Pre2[t & 1][((hi << 2) + r) * 4 + q] = p4[r];
            }
        }
        if (w == 14 && t >= 2) {   // layer-2 + FC at lag 2 (lanes 0..15 = batches)
            const int s = t - 2;
            if (l < 16) {
                const float zi = p2[0] + __builtin_fmaf(w2si, h2, nb2i);
                const float zf = p2[1] + __builtin_fmaf(w2sf, h2, nb2f);
                const float zg = p2[2] + __builtin_fmaf(w2sg, h2, tb2g);
                const float zo = p2[3] + __builtin_fmaf(w2so, h2, nb2o);
                h2 = cell_update(zi, zf, zg, zo, c2);
                Ybuf[l][s & 15] = __builtin_fmaf(fcw, h2, fcb);
            }
            if ((s & 15) == 15) {   // coalesced flush: 16 rows x 64B
                float* op = out + (size_t)(b0 + (l >> 2)) * 256 + (s - 15) + ((l & 3) << 2);
                *(f32x4*)op = *(const f32x4*)&Ybuf[l >> 2][(l & 3) << 2];
            }
        }

        // ---- in-wave 4x4 gate transpose across lanes q^4, q^8 ----
        float v0 = g[0], v1 = g[1], v2 = g[2], v3 = g[3];
        {
            const bool od = (q & 4);
            float x0 = od ? v0 : v1;
            float x1 = od ? v2 : v3;
            const float y0 = __shfl_xor(x0, 4, 64);
            const float y1 = __shfl_xor(x1, 4, 64);
            if (od) { v0 = y0; v2 = y1; } else { v1 = y0; v3 = y1; }
        }
        {
            const bool od = (q & 8);
            float x0 = od ? v0 : v2;
            float x1 = od ? v1 : v3;
            const float y0 = __shfl_xor(x0, 8, 64);
            const float y1 = __shfl_xor(x1, 8, 64);
            if (od) { v0 = y0; v1 = y1; } else { v2 = y0; v3 = y1; }
        }
        // lane now holds zi,zf,zg,zo of cell (batch bb, hidden he)
        const float hv = cell_update(v0, v1, v2, v3, cc);
        *(unsigned short*)((char*)A_h + ((t & 1) << 11) + awh) =
            __builtin_bit_cast(unsigned short, (__bf16)hv);

        __syncthreads();
    }

    // ---- epilogue: layer-2 s=254 (Pre2[1]) and s=255 (fresh proj of h_255) ----
    if (w == 15) {
        const u16x8 ra0 = *(const u16x8*)((const char*)A_h + 2048 + ar0);
        const u16x8 ra1 = *(const u16x8*)((const char*)A_h + 2048 + ar1);
        f32x4 p4 = {0.f, 0.f, 0.f, 0.f};
        p4 = __builtin_amdgcn_mfma_f32_16x16x32_bf16(__builtin_bit_cast(bf16x8, ra0), B2[0], p4, 0, 0, 0);
        p4 = __builtin_amdgcn_mfma_f32_16x16x32_bf16(__builtin_bit_cast(bf16x8, ra1), B2[1], p4, 0, 0, 0);
        if (q < 4) {
            #pragma unroll
            for (int r = 0; r < 4; ++r) Pre2[0][((hi << 2) + r) * 4 + q] = p4[r];
        }
    }
    __syncthreads();
    if (w == 14) {
        if (l < 16) {
            #pragma unroll
            for (int e = 0; e < 2; ++e) {   // e=0 -> s=254 (Pre2[1]), e=1 -> s=255 (Pre2[0])
                const f32x4 p2 = *(const f32x4*)&Pre2[1 - e][l << 2];
                const float zi = p2[0] + __builtin_fmaf(w2si, h2, nb2i);
                const float zf = p2[1] + __builtin_fmaf(w2sf, h2, nb2f);
                const float zg = p2[2] + __builtin_fmaf(w2sg, h2, tb2g);
                const float zo = p2[3] + __builtin_fmaf(w2so, h2, nb2o);
                h2 = cell_update(zi, zf, zg, zo, c2);
                Ybuf[l][14 + e] = __builtin_fmaf(fcw, h2, fcb);
            }
        }
        float* op = out + (size_t)(b0 + (l >> 2)) * 256 + 240 + ((l & 3) << 2);
        *(f32x4*)op = *(const f32x4*)&Ybuf[l >> 2][(l & 3) << 2];
    }
}

extern "C" void kernel_launch(void* const* d_in, const int* in_sizes, int n_in,
                              void* d_out, int out_size, void* d_ws, size_t ws_size,
                              hipStream_t stream) {
    (void)in_sizes; (void)n_in; (void)out_size; (void)d_ws; (void)ws_size;
    const float* x     = (const float*)d_in[0];
    const float* w_ih1 = (const float*)d_in[1];
    const float* w_hh1 = (const float*)d_in[2];
    const float* b_ih1 = (const float*)d_in[3];
    const float* b_hh1 = (const float*)d_in[4];
    const float* w_ih2 = (const float*)d_in[5];
    const float* w_hh2 = (const float*)d_in[6];
    const float* b_ih2 = (const float*)d_in[7];
    const float* b_hh2 = (const float*)d_in[8];
    const float* fc_w  = (const float*)d_in[9];
    const float* fc_b  = (const float*)d_in[10];
    lstm_fused<<<dim3(256), dim3(1024), 0, stream>>>(
        x, w_ih1, w_hh1, b_ih1, b_hh1, w_ih2, w_hh2, b_ih2, b_hh2, fc_w, fc_b,
        (float*)d_out);
}

// Round 9
// 167.427 us; speedup vs baseline: 1.1561x; 1.1561x over previous
//
#include <hip/hip_runtime.h>

typedef float  f32x4  __attribute__((ext_vector_type(4)));
typedef __bf16 bf16x8 __attribute__((ext_vector_type(8)));
typedef unsigned short u16x8 __attribute__((ext_vector_type(8)));

#define NL2E (-1.44269504088896f)   // -log2(e)
#define TL2E ( 2.88539008177793f)   // 2*log2(e)

__device__ __forceinline__ float rcpf(float x) { return __builtin_amdgcn_rcpf(x); }
__device__ __forceinline__ float ex2(float x)  { return __builtin_amdgcn_exp2f(x); }

// LSTM cell, pre-scaled gate args (zi,zf,zo = -log2e*pre, zg = 2log2e*pre)
__device__ __forceinline__ float cell_update(float zi, float zf, float zg, float zo, float& c) {
    const float Ei = ex2(zi), Ef = ex2(zf), Eg = ex2(zg), Eo = ex2(zo);
    const float ig = (Eg - 1.0f) * rcpf((1.0f + Ei) * (1.0f + Eg));
    const float fv = rcpf(1.0f + Ef);
    c = __builtin_fmaf(fv, c, ig);
    const float zc = fminf(fmaxf(TL2E * c, -60.0f), 60.0f);
    const float Ec = ex2(zc);
    return (Ec - 1.0f) * rcpf((1.0f + Eo) * (1.0f + Ec));   // o*tanh(c)
}

// 16 batches/WG, 512 threads = 8 waves, grid 256 -> 2 waves/SIMD (overlap!)
// Wave w owns hiddens [8w,8w+8) via 2 gate-pair tiles:
//   T0 cols: gate (c>>3) in {i,f}, hidden 8w+(c&7); T1: gate 2+(c>>3) in {g,o}.
// Missing gate pair lives on lane q^8 (same wave) -> ONE shfl_xor stage.
// Lane q<8 updates batches 4hi+{0,1}; q>=8: 4hi+{2,3} (2 cells/lane).
// Per wave: 6 MFMA, 16 trans, ~70 VALU = half of R3 -> 2 streams/SIMD hide
// each other's latencies; one 8-wave barrier per step.
__global__ __launch_bounds__(512, 1) void lstm_fused(
    const float* __restrict__ x,      // [4096][256][16]
    const float* __restrict__ w_ih1,  // [256][16]
    const float* __restrict__ w_hh1,  // [256][64]
    const float* __restrict__ b_ih1, const float* __restrict__ b_hh1,
    const float* __restrict__ w_ih2,  // [4][64]
    const float* __restrict__ w_hh2,  // [4]
    const float* __restrict__ b_ih2, const float* __restrict__ b_hh2,
    const float* __restrict__ fc_w, const float* __restrict__ fc_b,
    float* __restrict__ out)          // [4096][256]
{
    __shared__ unsigned short A_h[2 * 16 * 64];        // 4KB dbuf h1 bf16 [buf][b][he], ^((b&7)<<4)
    __shared__ unsigned short Xc[2 * 16 * 16 * 32];    // 32KB dbuf x bf16 [buf][b][tt][k]
    __shared__ float Pre2[2][64];                      // dbuf layer-2 preacts [buf][b*4+g]
    __shared__ float Ybuf[16][16];                     // [b][tt] (wave-6 private)

    const int tid = threadIdx.x;
    const int w   = tid >> 6;        // wave 0..7
    const int l   = tid & 63;
    const int q   = l & 15;
    const int hi  = l >> 4;
    const int qh  = q >> 3;          // gate-half of this lane's columns
    const int b0  = blockIdx.x << 4;
    const int sw  = (q & 7) << 4;
    const u16x8 z8 = {0,0,0,0,0,0,0,0};

    if (tid < 256) ((u16x8*)A_h)[tid] = z8;            // zero both A_h bufs
    {   // zero Xc pad halves (k=16..31) in both bufs, once: 512 rows x 32B
        const int buf = tid >> 8, zb = (tid >> 4) & 15, ztt = tid & 15;
        char* zp = (char*)Xc + buf * 16384 + zb * 1024;
        *(u16x8*)(zp + ((ztt * 64 + 32) ^ ((zb & 7) << 4))) = z8;
        *(u16x8*)(zp + ((ztt * 64 + 48) ^ ((zb & 7) << 4))) = z8;
    }

    // ---- B fragments: 2 gate-pair tiles per wave, pre-scaled ----
    const int hb8 = w << 3;
    bf16x8 Bf[2][3];
    float accb[2];
    #pragma unroll
    for (int tile = 0; tile < 2; ++tile) {
        const int gate = (tile << 1) + qh;             // T0: 0/1, T1: 2/3
        const int gcol = (gate << 6) + hb8 + (q & 7);
        const float sc = (gate == 2) ? TL2E : NL2E;
        #pragma unroll
        for (int ks = 0; ks < 3; ++ks) {
            bf16x8 tmp;
            #pragma unroll
            for (int j = 0; j < 8; ++j) {
                const int k = ks * 32 + hi * 8 + j;
                float v = 0.f;
                if (k < 64)      v = w_hh1[gcol * 64 + k];
                else if (k < 80) v = w_ih1[gcol * 16 + (k - 64)];
                tmp[j] = (__bf16)(sc * v);
            }
            Bf[tile][ks] = tmp;
        }
        accb[tile] = sc * (b_ih1[gcol] + b_hh1[gcol]);
    }
    bf16x8 B2[2];                                      // layer-2 proj (wave 7)
    {
        const float sc2 = (q == 2) ? TL2E : NL2E;
        #pragma unroll
        for (int ks = 0; ks < 2; ++ks) {
            bf16x8 tmp;
            #pragma unroll
            for (int j = 0; j < 8; ++j) {
                const int k = ks * 32 + hi * 8 + j;
                const float v = (q < 4) ? w_ih2[q * 64 + k] : 0.f;
                tmp[j] = (__bf16)(sc2 * v);
            }
            B2[ks] = tmp;
        }
    }

    // layer-2 constants (scaled)
    const float w2si = NL2E * w_hh2[0], w2sf = NL2E * w_hh2[1];
    const float w2sg = TL2E * w_hh2[2], w2so = NL2E * w_hh2[3];
    const float nb2i = NL2E * (b_ih2[0] + b_hh2[0]);
    const float nb2f = NL2E * (b_ih2[1] + b_hh2[1]);
    const float tb2g = TL2E * (b_ih2[2] + b_hh2[2]);
    const float nb2o = NL2E * (b_ih2[3] + b_hh2[3]);
    const float fcw = fc_w[0], fcb = fc_b[0];

    // ---- x staging: thread (bx,part,half) owns x[b0+bx][t0+part][half*8..+7] ----
    const int bx = tid >> 5, rem = tid & 31, part = rem >> 1, half = rem & 1;
    const unsigned xoff = (unsigned)(bx * 1024 + ((part * 64 + half * 16) ^ ((bx & 7) << 4)));
    const float* xrow = x + (size_t)(b0 + bx) * 4096 + part * 16 + half * 8;
    f32x4 xqa, xqb;
    auto ldx = [&](int t) {
        const float* p = xrow + t * 16;
        xqa = ((const f32x4*)p)[0]; xqb = ((const f32x4*)p)[1];
    };
    auto stage_x = [&](int bufoff) {
        bf16x8 v;
        #pragma unroll
        for (int j = 0; j < 4; ++j) { v[j] = (__bf16)xqa[j]; v[4 + j] = (__bf16)xqb[j]; }
        *(u16x8*)((char*)Xc + bufoff + xoff) = __builtin_bit_cast(u16x8, v);
    };
    ldx(0); stage_x(0); ldx(16);

    // invariant addresses
    const unsigned ar0 = (unsigned)((q * 128 +      hi * 16) ^ sw);
    const unsigned ar1 = (unsigned)((q * 128 + 64 + hi * 16) ^ sw);
    const int he = hb8 + (q & 7);                      // hidden this lane owns
    const int bA = (hi << 2) + (qh << 1);              // first batch this lane owns
    const int bB = bA + 1;
    const unsigned awA = (unsigned)(bA * 128 + ((he * 2) ^ ((bA & 7) << 4)));
    const unsigned awB = (unsigned)(bB * 128 + ((he * 2) ^ ((bB & 7) << 4)));

    float cA = 0.f, cB = 0.f;          // layer-1 cell states (2 cells/lane)
    float h2 = 0.f, c2 = 0.f;          // layer-2 state (wave 6, lanes 0..15)

    __syncthreads();

    #pragma unroll 2
    for (int t = 0; t < 256; ++t) {
        const int tt = t & 15;
        if (tt == 0 && t + 16 < 256) {
            stage_x(((((t >> 4) + 1) & 1)) << 14);
            if (t + 32 < 256) ldx(t + 32);
        }

        const int rb = ((t + 1) & 1) << 11;
        const u16x8 ra0 = *(const u16x8*)((const char*)A_h + rb + ar0);
        const u16x8 ra1 = *(const u16x8*)((const char*)A_h + rb + ar1);
        const u16x8 ra2 = *(const u16x8*)((const char*)Xc + (((t >> 4) & 1) << 14)
                                          + ((q * 1024 + (tt << 6) + (hi << 4)) ^ sw));

        const bf16x8 a0 = __builtin_bit_cast(bf16x8, ra0);
        const bf16x8 a1 = __builtin_bit_cast(bf16x8, ra1);
        const bf16x8 a2 = __builtin_bit_cast(bf16x8, ra2);

        f32x4 T0 = {accb[0], accb[0], accb[0], accb[0]};
        f32x4 T1 = {accb[1], accb[1], accb[1], accb[1]};
        T0 = __builtin_amdgcn_mfma_f32_16x16x32_bf16(a2, Bf[0][2], T0, 0, 0, 0);
        T1 = __builtin_amdgcn_mfma_f32_16x16x32_bf16(a2, Bf[1][2], T1, 0, 0, 0);
        T0 = __builtin_amdgcn_mfma_f32_16x16x32_bf16(a0, Bf[0][0], T0, 0, 0, 0);
        T1 = __builtin_amdgcn_mfma_f32_16x16x32_bf16(a0, Bf[1][0], T1, 0, 0, 0);
        T0 = __builtin_amdgcn_mfma_f32_16x16x32_bf16(a1, Bf[0][1], T0, 0, 0, 0);
        T1 = __builtin_amdgcn_mfma_f32_16x16x32_bf16(a1, Bf[1][1], T1, 0, 0, 0);

        if (w == 7) {   // layer-2 input projection of h_{t-1} -> Pre2[t&1]
            f32x4 p4 = {0.f, 0.f, 0.f, 0.f};
            p4 = __builtin_amdgcn_mfma_f32_16x16x32_bf16(a0, B2[0], p4, 0, 0, 0);
            p4 = __builtin_amdgcn_mfma_f32_16x16x32_bf16(a1, B2[1], p4, 0, 0, 0);
            if (q < 4) {
                #pragma unroll
                for (int r = 0; r < 4; ++r) Pre2[t & 1][((hi << 2) + r) * 4 + q] = p4[r];
            }
        }
        if (w == 6 && t >= 2) {   // layer-2 + FC at lag 2 (lanes 0..15 = batches)
            const int s = t - 2;
            if (l < 16) {
                const f32x4 p2 = *(const f32x4*)&Pre2[(t + 1) & 1][l << 2];
                const float zi = p2[0] + __builtin_fmaf(w2si, h2, nb2i);
                const float zf = p2[1] + __builtin_fmaf(w2sf, h2, nb2f);
                const float zg = p2[2] + __builtin_fmaf(w2sg, h2, tb2g);
                const float zo = p2[3] + __builtin_fmaf(w2so, h2, nb2o);
                h2 = cell_update(zi, zf, zg, zo, c2);
                Ybuf[l][s & 15] = __builtin_fmaf(fcw, h2, fcb);
            }
            if ((s & 15) == 15) {   // coalesced flush: 16 rows x 64B
                float* op = out + (size_t)(b0 + (l >> 2)) * 256 + (s - 15) + ((l & 3) << 2);
                *(f32x4*)op = *(const f32x4*)&Ybuf[l >> 2][(l & 3) << 2];
            }
        }

        // ---- one-stage gate-pair exchange with lane q^8 ----
        const bool lo = (qh == 0);
        const float s1 = lo ? T0[2] : T0[0];
        const float s2 = lo ? T0[3] : T0[1];
        const float s3 = lo ? T1[2] : T1[0];
        const float s4 = lo ? T1[3] : T1[1];
        const float r1 = __shfl_xor(s1, 8, 64);
        const float r2 = __shfl_xor(s2, 8, 64);
        const float r3 = __shfl_xor(s3, 8, 64);
        const float r4 = __shfl_xor(s4, 8, 64);
        const float ziA = lo ? T0[0] : r1,  ziB = lo ? T0[1] : r2;
        const float zfA = lo ? r1 : T0[2],  zfB = lo ? r2 : T0[3];
        const float zgA = lo ? T1[0] : r3,  zgB = lo ? T1[1] : r4;
        const float zoA = lo ? r3 : T1[2],  zoB = lo ? r4 : T1[3];

        // ---- 2 cells/lane; write h_t to buf t&1 ----
        char* AW = (char*)A_h + ((t & 1) << 11);
        const float hvA = cell_update(ziA, zfA, zgA, zoA, cA);
        *(unsigned short*)(AW + awA) = __builtin_bit_cast(unsigned short, (__bf16)hvA);
        const float hvB = cell_update(ziB, zfB, zgB, zoB, cB);
        *(unsigned short*)(AW + awB) = __builtin_bit_cast(unsigned short, (__bf16)hvB);

        __syncthreads();
    }

    // ---- epilogue: layer-2 s=254 (Pre2[1]) and s=255 (fresh proj of h_255) ----
    if (w == 7) {
        const u16x8 ra0 = *(const u16x8*)((const char*)A_h + 2048 + ar0);
        const u16x8 ra1 = *(const u16x8*)((const char*)A_h + 2048 + ar1);
        f32x4 p4 = {0.f, 0.f, 0.f, 0.f};
        p4 = __builtin_amdgcn_mfma_f32_16x16x32_bf16(__builtin_bit_cast(bf16x8, ra0), B2[0], p4, 0, 0, 0);
        p4 = __builtin_amdgcn_mfma_f32_16x16x32_bf16(__builtin_bit_cast(bf16x8, ra1), B2[1], p4, 0, 0, 0);
        if (q < 4) {
            #pragma unroll
            for (int r = 0; r < 4; ++r) Pre2[0][((hi << 2) + r) * 4 + q] = p4[r];
        }
    }
    __syncthreads();
    if (w == 6) {
        if (l < 16) {
            #pragma unroll
            for (int e = 0; e < 2; ++e) {   // e=0 -> s=254 (Pre2[1]), e=1 -> s=255 (Pre2[0])
                const f32x4 p2 = *(const f32x4*)&Pre2[1 - e][l << 2];
                const float zi = p2[0] + __builtin_fmaf(w2si, h2, nb2i);
                const float zf = p2[1] + __builtin_fmaf(w2sf, h2, nb2f);
                const float zg = p2[2] + __builtin_fmaf(w2sg, h2, tb2g);
                const float zo = p2[3] + __builtin_fmaf(w2so, h2, nb2o);
                h2 = cell_update(zi, zf, zg, zo, c2);
                Ybuf[l][14 + e] = __builtin_fmaf(fcw, h2, fcb);
            }
        }
        float* op = out + (size_t)(b0 + (l >> 2)) * 256 + 240 + ((l & 3) << 2);
        *(f32x4*)op = *(const f32x4*)&Ybuf[l >> 2][(l & 3) << 2];
    }
}

extern "C" void kernel_launch(void* const* d_in, const int* in_sizes, int n_in,
                              void* d_out, int out_size, void* d_ws, size_t ws_size,
                              hipStream_t stream) {
    (void)in_sizes; (void)n_in; (void)out_size; (void)d_ws; (void)ws_size;
    const float* x     = (const float*)d_in[0];
    const float* w_ih1 = (const float*)d_in[1];
    const float* w_hh1 = (const float*)d_in[2];
    const float* b_ih1 = (const float*)d_in[3];
    const float* b_hh1 = (const float*)d_in[4];
    const float* w_ih2 = (const float*)d_in[5];
    const float* w_hh2 = (const float*)d_in[6];
    const float* b_ih2 = (const float*)d_in[7];
    const float* b_hh2 = (const float*)d_in[8];
    const float* fc_w  = (const float*)d_in[9];
    const float* fc_b  = (const float*)d_in[10];
    lstm_fused<<<dim3(256), dim3(512), 0, stream>>>(
        x, w_ih1, w_hh1, b_ih1, b_hh1, w_ih2, w_hh2, b_ih2, b_hh2, fc_w, fc_b,
        (float*)d_out);
}